// Round 1
// baseline (3234.332 us; speedup 1.0000x reference)
//
#include <hip/hip_runtime.h>
#include <math.h>

#define BB 8
#define NN 4096
#define LL 32
#define DD 64
#define SS 64
#define NLV 2

// workspace layout (floats)
#define W2_OFF 0
#define B2_OFF (NLV*DD*192)            // 24576
#define V_OFF  (B2_OFF + NLV*192)      // 24960
#define SM_OFF (V_OFF + NLV*DD)        // 25088
// total 25090 floats ~= 100 KB

// ---------------- prep: combined weights ----------------
// W2[l][d][col] = sum_e lpW[l][d][e] * pW[l][e][col]
// b2[l][col]    = sum_e lpb[l][e]   * pW[l][e][col] + pb[l][col]
// v[l][d]       = (1/64) sum_e lpW[l][d][e]
// s[l]          = (1/64) sum_e lpb[l][e]
__global__ void prep_kernel(const float* __restrict__ lpW, const float* __restrict__ lpb,
                            const float* __restrict__ pW,  const float* __restrict__ pb,
                            float* __restrict__ ws) {
    int blk = blockIdx.x;             // 0 .. NLV*192-1
    int l = blk / 192, col = blk % 192;
    int d = threadIdx.x;              // 0..63
    const float* lpWl = lpW + l * DD * DD;
    const float* pWl  = pW  + l * DD * 192;

    float acc = 0.f;
    for (int e = 0; e < DD; ++e) acc = fmaf(lpWl[d * DD + e], pWl[e * 192 + col], acc);
    ws[W2_OFF + (l * DD + d) * 192 + col] = acc;

    if (d == 0) {
        float bb = pb[l * 192 + col];
        for (int e = 0; e < DD; ++e) bb = fmaf(lpb[l * DD + e], pWl[e * 192 + col], bb);
        ws[B2_OFF + l * 192 + col] = bb;
    }
    if (col == 0) {
        float sv = 0.f;
        for (int e = 0; e < DD; ++e) sv += lpWl[d * DD + e];
        ws[V_OFF + l * DD + d] = sv * (1.f / 64.f);
        if (d == 0) {
            float ss = 0.f;
            for (int e = 0; e < DD; ++e) ss += lpb[l * DD + e];
            ws[SM_OFF + l] = ss * (1.f / 64.f);
        }
    }
}

// ---------------- main: one wave per (b,n) pair ----------------
__global__ __launch_bounds__(256) void mlm_kernel(
    const float* __restrict__ p_seq,
    const float* __restrict__ oW, const float* __restrict__ ob,
    const float* __restrict__ rW, const float* __restrict__ rb,
    const float* __restrict__ fW, const float* __restrict__ fb,
    const float* __restrict__ ws, float* __restrict__ out) {

    const int lane = threadIdx.x & 63;
    const int wid  = threadIdx.x >> 6;
    const int pair = blockIdx.x * 4 + wid;            // 0 .. 32767

    const float* rowbase = p_seq + (size_t)pair * (LL * DD);
    const float* W2 = ws + W2_OFF;
    const float* b2 = ws + B2_OFF;
    const float* vv = ws + V_OFF;
    const float* sm = ws + SM_OFF;

    float ypart = 0.f;

    #pragma unroll 1
    for (int l = 0; l < NLV; ++l) {
        const float* W2l = W2 + l * DD * 192;
        // per-lane weight columns (a-col `lane`, b-col `64+lane`) in registers
        float w0[DD], w1[DD];
        #pragma unroll
        for (int d = 0; d < DD; ++d) {
            w0[d] = W2l[d * 192 + lane];
            w1[d] = W2l[d * 192 + 64 + lane];
        }
        const float b2a  = b2[l * 192 + lane];
        const float b2b  = b2[l * 192 + 64 + lane];
        const float vreg = vv[l * DD + lane];
        const float sreg = sm[l];

        float h = 0.f, xm_last = 0.f;

        #pragma unroll 1
        for (int t = 0; t < LL; ++t) {
            const float* rowp = rowbase + t * DD;
            // distributed element for the xm reduction
            float rv = rowp[lane];
            float part = rv * vreg;
            #pragma unroll
            for (int off = 32; off >= 1; off >>= 1) part += __shfl_xor(part, off, 64);
            float xm = part + sreg;

            // a/b dot products: row broadcast via wave-uniform float4 loads (L1)
            float acc0 = b2a, acc1 = b2b;
            const float4* r4 = (const float4*)rowp;
            #pragma unroll
            for (int k = 0; k < 16; ++k) {
                float4 r = r4[k];
                acc0 = fmaf(r.x, w0[4*k+0], acc0); acc1 = fmaf(r.x, w1[4*k+0], acc1);
                acc0 = fmaf(r.y, w0[4*k+1], acc0); acc1 = fmaf(r.y, w1[4*k+1], acc1);
                acc0 = fmaf(r.z, w0[4*k+2], acc0); acc1 = fmaf(r.z, w1[4*k+2], acc1);
                acc0 = fmaf(r.w, w0[4*k+3], acc0); acc1 = fmaf(r.w, w1[4*k+3], acc1);
            }
            float a = 1.f / (1.f + __expf(-acc0));
            h = fmaf(a, h, acc1 * xm);
            if (t == LL - 1) xm_last = xm;
        }

        // ---- epilogue (per pair, per level) ----
        // c at last timestep: reuse last row (L1-hot), weights from global
        float accc = b2[l * 192 + 128 + lane];
        {
            const float4* r4 = (const float4*)(rowbase + (LL - 1) * DD);
            #pragma unroll
            for (int k = 0; k < 16; ++k) {
                float4 r = r4[k];
                accc = fmaf(r.x, W2l[(4*k+0) * 192 + 128 + lane], accc);
                accc = fmaf(r.y, W2l[(4*k+1) * 192 + 128 + lane], accc);
                accc = fmaf(r.z, W2l[(4*k+2) * 192 + 128 + lane], accc);
                accc = fmaf(r.w, W2l[(4*k+3) * 192 + 128 + lane], accc);
            }
        }
        float ch = accc * h;
        float g  = 0.5f * ch * (1.f + erff(ch * 0.70710678118654752f));

        // o = g_vec @ oW + ob   (broadcast g via shfl)
        const float* oWl = oW + l * DD * SS;
        float o = ob[l * SS + lane];
        #pragma unroll
        for (int e = 0; e < DD; ++e) {
            float ge = __shfl(g, e, 64);
            o = fmaf(ge, oWl[e * SS + lane], o);
        }
        float last = o + xm_last;

        // feat = last @ rW + rb
        const float* rWl = rW + l * SS * SS;
        float f = rb[l * SS + lane];
        #pragma unroll
        for (int e = 0; e < SS; ++e) {
            float le = __shfl(last, e, 64);
            f = fmaf(le, rWl[e * SS + lane], f);
        }
        ypart = fmaf(f, fW[l * SS + lane], ypart);
    }

    #pragma unroll
    for (int off = 32; off >= 1; off >>= 1) ypart += __shfl_xor(ypart, off, 64);
    if (lane == 0) out[pair] = ypart + fb[0];
}

extern "C" void kernel_launch(void* const* d_in, const int* in_sizes, int n_in,
                              void* d_out, int out_size, void* d_ws, size_t ws_size,
                              hipStream_t stream) {
    const float* p_seq = (const float*)d_in[0];
    const float* lp_W  = (const float*)d_in[1];
    const float* lp_b  = (const float*)d_in[2];
    const float* pW    = (const float*)d_in[3];
    const float* pb    = (const float*)d_in[4];
    const float* oW    = (const float*)d_in[5];
    const float* ob    = (const float*)d_in[6];
    const float* rW    = (const float*)d_in[7];
    const float* rb    = (const float*)d_in[8];
    const float* fW    = (const float*)d_in[9];
    const float* fb    = (const float*)d_in[10];

    float* ws  = (float*)d_ws;
    float* out = (float*)d_out;

    prep_kernel<<<NLV * 192, 64, 0, stream>>>(lp_W, lp_b, pW, pb, ws);

    const int pairs = BB * NN;          // 32768
    mlm_kernel<<<pairs / 4, 256, 0, stream>>>(p_seq, oW, ob, rW, rb, fW, fb, ws, out);
}

// Round 2
// 219.347 us; speedup vs baseline: 14.7453x; 14.7453x over previous
//
#include <hip/hip_runtime.h>
#include <math.h>

using s16x8  = __attribute__((ext_vector_type(8)))  short;
using f32x16 = __attribute__((ext_vector_type(16))) float;

#define BB 8
#define NN 4096
#define LL 32
#define DD 64
#define SS 64
#define NLV 2

// ws layout (float indices)
#define WEXT_OFF 0                      // [2][64][224] fp32 combined weights
#define BIAS_OFF 28672                  // [2][224]
#define WVEC_OFF 29120                  // [2][64]  w_l = oW @ (rW @ fW_seg)
#define SIG_OFF  29248                  // [2] sigma_l
#define BETA_OFF 29250                  // [2] beta_l
#define C0_OFF   29252                  // [2] rb.fWseg partials
#define FRAG_OFF 29256                  // bf16 B-fragments, byte off 117024 (16B aligned)
#define FRAG_BYTES_PER_LEVEL 57344      // 7 nt * 4 ks * 2 (hi/lo) * 64 lanes * 16B

// ------------------------------------------------------------------
// prep1: Wext = [lpW@pW_a | lpW@pW_b | rowmean(lpW) x32 | lpW@pW_c] (64x224 per level)
//        biasext, and the collapsed epilogue vectors/scalars.
// ------------------------------------------------------------------
__global__ void prep1(const float* __restrict__ lpW, const float* __restrict__ lpb,
                      const float* __restrict__ pW,  const float* __restrict__ pb,
                      const float* __restrict__ oW,  const float* __restrict__ ob,
                      const float* __restrict__ rW,  const float* __restrict__ rb,
                      const float* __restrict__ fW,  float* __restrict__ ws) {
    __shared__ float q[64];
    int blk = blockIdx.x;
    int d = threadIdx.x;                 // 0..63
    if (blk < 2 * 224) {
        int l = blk / 224, j = blk % 224;
        const float* lpWl = lpW + l * 64 * 64;
        const float* pWl  = pW  + l * 64 * 192;
        float wv;
        if (j < 128) {                   // a (0-63) and b (64-127) columns
            int col = j;
            float acc = 0.f;
            for (int e = 0; e < 64; ++e) acc = fmaf(lpWl[d * 64 + e], pWl[e * 192 + col], acc);
            wv = acc;
            if (d == 0) {
                float bb = pb[l * 192 + col];
                for (int e = 0; e < 64; ++e) bb = fmaf(lpb[l * 64 + e], pWl[e * 192 + col], bb);
                ws[BIAS_OFF + l * 224 + j] = bb;
            }
        } else if (j < 160) {            // xm columns: u replicated x32
            float s = 0.f;
            for (int e = 0; e < 64; ++e) s += lpWl[d * 64 + e];
            wv = s * (1.f / 64.f);
            if (d == 0) {
                float ss = 0.f;
                for (int e = 0; e < 64; ++e) ss += lpb[l * 64 + e];
                ws[BIAS_OFF + l * 224 + j] = ss * (1.f / 64.f);
            }
        } else {                         // c columns (pW cols 128-191)
            int col = j - 32;
            float acc = 0.f;
            for (int e = 0; e < 64; ++e) acc = fmaf(lpWl[d * 64 + e], pWl[e * 192 + col], acc);
            wv = acc;
            if (d == 0) {
                float bb = pb[l * 192 + col];
                for (int e = 0; e < 64; ++e) bb = fmaf(lpb[l * 64 + e], pWl[e * 192 + col], bb);
                ws[BIAS_OFF + l * 224 + j] = bb;
            }
        }
        ws[WEXT_OFF + (l * 64 + d) * 224 + j] = wv;
    } else {
        // collapsed epilogue: q = rW @ fWseg; wvec = oW @ q; sigma, beta, C0 partial
        int l = blk - 2 * 224;           // 0..1
        float qv = 0.f;
        for (int j2 = 0; j2 < 64; ++j2) qv = fmaf(rW[l * 4096 + d * 64 + j2], fW[l * 64 + j2], qv);
        q[d] = qv;
        __syncthreads();
        float wv = 0.f;
        for (int s = 0; s < 64; ++s) wv = fmaf(oW[l * 4096 + d * 64 + s], q[s], wv);
        ws[WVEC_OFF + l * 64 + d] = wv;
        if (d == 0) { float s = 0.f; for (int i = 0; i < 64; ++i) s += q[i];               ws[SIG_OFF  + l] = s; }
        if (d == 1) { float s = 0.f; for (int i = 0; i < 64; ++i) s += ob[l*64+i] * q[i];  ws[BETA_OFF + l] = s; }
        if (d == 2) { float s = 0.f; for (int i = 0; i < 64; ++i) s += rb[l*64+i] * fW[l*64+i]; ws[C0_OFF + l] = s; }
    }
}

// ------------------------------------------------------------------
// prep2: pack Wext into bf16 hi/lo B-operand fragments for mfma_f32_32x32x16_bf16.
// B layout: lane holds B[k][col]: col = lane&31, k = ks*16 + 4*(lane>>5) + (i&3) + 8*(i>>2)
// ------------------------------------------------------------------
__global__ void prep2(float* __restrict__ ws) {
    int blk = blockIdx.x;                // l*28 + nt*4 + ks
    int l = blk / 28, r = blk % 28, nt = r / 4, ks = r % 4;
    int lane = threadIdx.x;
    const float* W = ws + WEXT_OFF + l * 64 * 224;
    s16x8 vh, vl;
#pragma unroll
    for (int i = 0; i < 8; ++i) {
        int k   = ks * 16 + ((lane >> 5) << 2) + (i & 3) + ((i >> 2) << 3);
        int col = nt * 32 + (lane & 31);
        float x = W[k * 224 + col];
        unsigned u = __float_as_uint(x);
        float hf = __uint_as_float(u & 0xffff0000u);
        vh[i] = (short)(u >> 16);
        vl[i] = (short)(__float_as_uint(x - hf) >> 16);
    }
    char* base = reinterpret_cast<char*>(ws) + (size_t)FRAG_OFF * 4 + (size_t)blk * 2048 + lane * 16;
    *reinterpret_cast<s16x8*>(base)        = vh;
    *reinterpret_cast<s16x8*>(base + 1024) = vl;
}

// ------------------------------------------------------------------
// main: 1 wave per (b,n) pair; 8 waves/block; B-frags staged in LDS per level.
// ------------------------------------------------------------------
#define BFR(nt, ks, hl) (*reinterpret_cast<const s16x8*>(smem + (((nt)*4+(ks))*2+(hl))*1024 + lane16))

#define ACCINIT(acc, bval) do { float _b = (bval); _Pragma("unroll") \
    for (int _r = 0; _r < 16; ++_r) acc[_r] = _b; } while (0)

#define MM1(nt, acc) do { _Pragma("unroll") \
    for (int ks = 0; ks < 4; ++ks) { \
        s16x8 bh = BFR(nt, ks, 0), bl = BFR(nt, ks, 1); \
        acc = __builtin_amdgcn_mfma_f32_32x32x16_bf16(Ah[ks], bh, acc, 0, 0, 0); \
        acc = __builtin_amdgcn_mfma_f32_32x32x16_bf16(Al[ks], bh, acc, 0, 0, 0); \
        acc = __builtin_amdgcn_mfma_f32_32x32x16_bf16(Ah[ks], bl, acc, 0, 0, 0); \
    } } while (0)

#define MM2(ntA, ntB, accA, accB) do { _Pragma("unroll") \
    for (int ks = 0; ks < 4; ++ks) { \
        s16x8 bhA = BFR(ntA, ks, 0), blA = BFR(ntA, ks, 1); \
        s16x8 bhB = BFR(ntB, ks, 0), blB = BFR(ntB, ks, 1); \
        accA = __builtin_amdgcn_mfma_f32_32x32x16_bf16(Ah[ks], bhA, accA, 0, 0, 0); \
        accB = __builtin_amdgcn_mfma_f32_32x32x16_bf16(Ah[ks], bhB, accB, 0, 0, 0); \
        accA = __builtin_amdgcn_mfma_f32_32x32x16_bf16(Al[ks], bhA, accA, 0, 0, 0); \
        accB = __builtin_amdgcn_mfma_f32_32x32x16_bf16(Al[ks], bhB, accB, 0, 0, 0); \
        accA = __builtin_amdgcn_mfma_f32_32x32x16_bf16(Ah[ks], blA, accA, 0, 0, 0); \
        accB = __builtin_amdgcn_mfma_f32_32x32x16_bf16(Ah[ks], blB, accB, 0, 0, 0); \
    } } while (0)

__global__ __launch_bounds__(512, 2) void mlm_mfma(
    const float* __restrict__ p_seq, const float* __restrict__ fb,
    const float* __restrict__ ws, float* __restrict__ out) {

    __shared__ __align__(16) char smem[FRAG_BYTES_PER_LEVEL];
    const int tid  = threadIdx.x;
    const int lane = tid & 63;
    const int wv   = tid >> 6;
    const int pair = blockIdx.x * 8 + wv;
    const int lane16 = lane * 16;
    const int row  = lane & 31;            // A-operand row = timestep t
    const int kofs = (lane >> 5) * 4;

    // ---- A fragments (shared by both levels): hi/lo bf16 split of X rows ----
    s16x8 Ah[4], Al[4];
    {
        const float* X = p_seq + (size_t)pair * (LL * DD) + row * 64 + kofs;
#pragma unroll
        for (int ks = 0; ks < 4; ++ks) {
            const float4 v0 = *reinterpret_cast<const float4*>(X + ks * 16);
            const float4 v1 = *reinterpret_cast<const float4*>(X + ks * 16 + 8);
            float f[8] = {v0.x, v0.y, v0.z, v0.w, v1.x, v1.y, v1.z, v1.w};
#pragma unroll
            for (int i = 0; i < 8; ++i) {
                unsigned u = __float_as_uint(f[i]);
                float hf = __uint_as_float(u & 0xffff0000u);
                Ah[ks][i] = (short)(u >> 16);
                Al[ks][i] = (short)(__float_as_uint(f[i] - hf) >> 16);
            }
        }
    }

    // scan over the 32 timesteps held in D-tile regs: t = (r&3) + 8*(r>>2) + 4*(lane>>5)
    const int myhalf = lane >> 5;
    auto scan_h = [&](const f32x16& aT, const f32x16& bT, const f32x16& xmT) -> float {
        float sig[16], bx[16];
#pragma unroll
        for (int r = 0; r < 16; ++r) {
            sig[r] = 1.f / (1.f + __expf(-aT[r]));
            bx[r]  = bT[r] * xmT[r];
        }
        float h = 0.f;
#pragma unroll
        for (int b = 0; b < 8; ++b) {
            const int rb = (b >> 1) * 4;
            float hh = h;
            hh = fmaf(sig[rb + 0], hh, bx[rb + 0]);
            hh = fmaf(sig[rb + 1], hh, bx[rb + 1]);
            hh = fmaf(sig[rb + 2], hh, bx[rb + 2]);
            hh = fmaf(sig[rb + 3], hh, bx[rb + 3]);
            float ho = __shfl_xor(hh, 32);
            h = (myhalf == (b & 1)) ? hh : ho;   // owner half keeps its value
        }
        return h;
    };

    float yp = 0.f;
    const float c0sum = ws[C0_OFF] + ws[C0_OFF + 1] + fb[0];

#pragma unroll 1
    for (int l = 0; l < 2; ++l) {
        __syncthreads();
        {   // stage this level's B-fragments into LDS (block-cooperative)
            const float4* src = reinterpret_cast<const float4*>(
                reinterpret_cast<const char*>(ws) + (size_t)FRAG_OFF * 4 + (size_t)l * FRAG_BYTES_PER_LEVEL);
            float4* dst = reinterpret_cast<float4*>(smem);
#pragma unroll
            for (int it = 0; it < 7; ++it) dst[tid + it * 512] = src[tid + it * 512];
        }
        __syncthreads();

        const float* bias = ws + BIAS_OFF + l * 224;
        const int col = lane & 31;

        f32x16 xmT; ACCINIT(xmT, bias[128 + col]);   // nt4: xm replicated columns
        MM1(4, xmT);

        f32x16 tA, tB;
        ACCINIT(tA, bias[0 + col]);   ACCINIT(tB, bias[64 + col]);   // nt0 (a, s 0-31), nt2 (b, s 0-31)
        MM2(0, 2, tA, tB);
        float h0 = scan_h(tA, tB, xmT);

        ACCINIT(tA, bias[32 + col]);  ACCINIT(tB, bias[96 + col]);   // nt1 (a, s 32-63), nt3 (b, s 32-63)
        MM2(1, 3, tA, tB);
        float h1 = scan_h(tA, tB, xmT);

        ACCINIT(tA, bias[160 + col]); ACCINIT(tB, bias[192 + col]);  // nt5, nt6: c columns
        MM2(5, 6, tA, tB);

        // epilogue: reg15 in upper half = t=31. y += sum_s gelu(c_s h_s) w_l[s] + xm31*sigma + beta
        if (lane >= 32) {
            float xml = xmT[15];
            float x0 = tA[15] * h0;                    // c[s=lane-32] * h[s=lane-32]
            float x1 = tB[15] * h1;                    // c[s=lane]    * h[s=lane]
            float g0 = 0.5f * x0 * (1.f + erff(x0 * 0.70710678118654752440f));
            float g1 = 0.5f * x1 * (1.f + erff(x1 * 0.70710678118654752440f));
            float term = g0 * ws[WVEC_OFF + l * 64 + (lane - 32)]
                       + g1 * ws[WVEC_OFF + l * 64 + lane];
            if (lane == 32) term += xml * ws[SIG_OFF + l] + ws[BETA_OFF + l];
            yp += term;
        }
    }

#pragma unroll
    for (int off = 16; off >= 1; off >>= 1) yp += __shfl_xor(yp, off);
    if (lane == 32) out[pair] = yp + c0sum;
}

extern "C" void kernel_launch(void* const* d_in, const int* in_sizes, int n_in,
                              void* d_out, int out_size, void* d_ws, size_t ws_size,
                              hipStream_t stream) {
    const float* p_seq = (const float*)d_in[0];
    const float* lp_W  = (const float*)d_in[1];
    const float* lp_b  = (const float*)d_in[2];
    const float* pW    = (const float*)d_in[3];
    const float* pb    = (const float*)d_in[4];
    const float* oW    = (const float*)d_in[5];
    const float* ob    = (const float*)d_in[6];
    const float* rW    = (const float*)d_in[7];
    const float* rb    = (const float*)d_in[8];
    const float* fW    = (const float*)d_in[9];
    const float* fb    = (const float*)d_in[10];

    float* ws  = (float*)d_ws;
    float* out = (float*)d_out;

    prep1<<<2 * 224 + 2, 64, 0, stream>>>(lp_W, lp_b, pW, pb, oW, ob, rW, rb, fW, ws);
    prep2<<<2 * 28, 64, 0, stream>>>(ws);

    const int pairs = BB * NN;               // 32768, 8 pairs per block
    mlm_mfma<<<pairs / 8, 512, 0, stream>>>(p_seq, fb, ws, out);
}

// Round 3
// 153.657 us; speedup vs baseline: 21.0491x; 1.4275x over previous
//
#include <hip/hip_runtime.h>
#include <math.h>

using s16x8  = __attribute__((ext_vector_type(8)))  short;
using f32x16 = __attribute__((ext_vector_type(16))) float;

#define BB 8
#define NN 4096
#define LL 32
#define DD 64
#define SS 64
#define NLV 2

// ws layout (float indices)
#define WEXT_OFF 0                      // [2][64][224] fp32 combined weights
#define BIAS_OFF 28672                  // [2][224]
#define WVEC_OFF 29120                  // [2][64]  w_l = oW @ (rW @ fW_seg)
#define SIG_OFF  29248                  // [2] sigma_l
#define BETA_OFF 29250                  // [2] beta_l
#define C0_OFF   29252                  // [2] rb.fWseg partials
#define FRAG_OFF 29256                  // bf16 B-fragments (hi only), byte 117024, 16B aligned
#define FRAG_BYTES_TOTAL 57344          // 2 lvl * 7 nt * 4 ks * 64 lanes * 16B

// ------------------------------------------------------------------
// prep1: Wext = [lpW@pW_a | lpW@pW_b | rowmean(lpW) x32 | lpW@pW_c] (64x224/level)
//        biasext + collapsed epilogue vectors/scalars.
// ------------------------------------------------------------------
__global__ void prep1(const float* __restrict__ lpW, const float* __restrict__ lpb,
                      const float* __restrict__ pW,  const float* __restrict__ pb,
                      const float* __restrict__ oW,  const float* __restrict__ ob,
                      const float* __restrict__ rW,  const float* __restrict__ rb,
                      const float* __restrict__ fW,  float* __restrict__ ws) {
    __shared__ float q[64];
    int blk = blockIdx.x;
    int d = threadIdx.x;                 // 0..63
    if (blk < 2 * 224) {
        int l = blk / 224, j = blk % 224;
        const float* lpWl = lpW + l * 64 * 64;
        const float* pWl  = pW  + l * 64 * 192;
        float wv;
        if (j < 128) {                   // a (0-63) and b (64-127) columns
            int col = j;
            float acc = 0.f;
            for (int e = 0; e < 64; ++e) acc = fmaf(lpWl[d * 64 + e], pWl[e * 192 + col], acc);
            wv = acc;
            if (d == 0) {
                float bb = pb[l * 192 + col];
                for (int e = 0; e < 64; ++e) bb = fmaf(lpb[l * 64 + e], pWl[e * 192 + col], bb);
                ws[BIAS_OFF + l * 224 + j] = bb;
            }
        } else if (j < 160) {            // xm columns: v replicated x32
            float s = 0.f;
            for (int e = 0; e < 64; ++e) s += lpWl[d * 64 + e];
            wv = s * (1.f / 64.f);
            if (d == 0) {
                float ss = 0.f;
                for (int e = 0; e < 64; ++e) ss += lpb[l * 64 + e];
                ws[BIAS_OFF + l * 224 + j] = ss * (1.f / 64.f);
            }
        } else {                         // c columns (pW cols 128-191)
            int col = j - 32;
            float acc = 0.f;
            for (int e = 0; e < 64; ++e) acc = fmaf(lpWl[d * 64 + e], pWl[e * 192 + col], acc);
            wv = acc;
            if (d == 0) {
                float bb = pb[l * 192 + col];
                for (int e = 0; e < 64; ++e) bb = fmaf(lpb[l * 64 + e], pWl[e * 192 + col], bb);
                ws[BIAS_OFF + l * 224 + j] = bb;
            }
        }
        ws[WEXT_OFF + (l * 64 + d) * 224 + j] = wv;
    } else {
        int l = blk - 2 * 224;           // 0..1
        float qv = 0.f;
        for (int j2 = 0; j2 < 64; ++j2) qv = fmaf(rW[l * 4096 + d * 64 + j2], fW[l * 64 + j2], qv);
        q[d] = qv;
        __syncthreads();
        float wv = 0.f;
        for (int s = 0; s < 64; ++s) wv = fmaf(oW[l * 4096 + d * 64 + s], q[s], wv);
        ws[WVEC_OFF + l * 64 + d] = wv;
        if (d == 0) { float s = 0.f; for (int i = 0; i < 64; ++i) s += q[i];               ws[SIG_OFF  + l] = s; }
        if (d == 1) { float s = 0.f; for (int i = 0; i < 64; ++i) s += ob[l*64+i] * q[i];  ws[BETA_OFF + l] = s; }
        if (d == 2) { float s = 0.f; for (int i = 0; i < 64; ++i) s += rb[l*64+i] * fW[l*64+i]; ws[C0_OFF + l] = s; }
    }
}

// ------------------------------------------------------------------
// prep2: pack Wext into RNE bf16 B-operand fragments (hi only).
// B layout (32x32x16): lane holds B[k][col], col=lane&31,
//   k = ks*16 + 4*(lane>>5) + (i&3) + 8*(i>>2)
// ------------------------------------------------------------------
__global__ void prep2(float* __restrict__ ws) {
    int blk = blockIdx.x;                // l*28 + nt*4 + ks
    int l = blk / 28, r = blk % 28, nt = r / 4, ks = r % 4;
    int lane = threadIdx.x;
    const float* W = ws + WEXT_OFF + l * 64 * 224;
    s16x8 vh;
#pragma unroll
    for (int i = 0; i < 8; ++i) {
        int k   = ks * 16 + ((lane >> 5) << 2) + (i & 3) + ((i >> 2) << 3);
        int col = nt * 32 + (lane & 31);
        unsigned u = __float_as_uint(W[k * 224 + col]);
        unsigned rn = u + 0x7fffu + ((u >> 16) & 1u);   // RNE to bf16
        vh[i] = (short)(rn >> 16);
    }
    char* base = reinterpret_cast<char*>(ws) + (size_t)FRAG_OFF * 4 + (size_t)blk * 1024 + lane * 16;
    *reinterpret_cast<s16x8*>(base) = vh;
}

// ------------------------------------------------------------------
// main: 1 wave per (b,n) pair; 8 waves/block; both levels' frags in LDS.
// ------------------------------------------------------------------
#define BFRD(l, nt, ks) (*reinterpret_cast<const s16x8*>(smem + ((((l)*7+(nt))*4+(ks)))*1024 + lane16))

#define ACCINIT(acc, bval) do { float _b = (bval); _Pragma("unroll") \
    for (int _r = 0; _r < 16; ++_r) acc[_r] = _b; } while (0)

// 2-term: (Ah + Al) x b_rne, two tiles interleaved for ILP
#define MMP(l, ntA, ntB, accA, accB) do { _Pragma("unroll") \
    for (int ks = 0; ks < 4; ++ks) { \
        s16x8 bA = BFRD(l, ntA, ks), bB = BFRD(l, ntB, ks); \
        accA = __builtin_amdgcn_mfma_f32_32x32x16_bf16(Ah[ks], bA, accA, 0, 0, 0); \
        accB = __builtin_amdgcn_mfma_f32_32x32x16_bf16(Ah[ks], bB, accB, 0, 0, 0); \
        accA = __builtin_amdgcn_mfma_f32_32x32x16_bf16(Al[ks], bA, accA, 0, 0, 0); \
        accB = __builtin_amdgcn_mfma_f32_32x32x16_bf16(Al[ks], bB, accB, 0, 0, 0); \
    } } while (0)

// 1-term xm tile (rank-1, replicated columns)
#define MX1(l, acc) do { _Pragma("unroll") \
    for (int ks = 0; ks < 4; ++ks) { \
        s16x8 b = BFRD(l, 4, ks); \
        acc = __builtin_amdgcn_mfma_f32_32x32x16_bf16(Ah[ks], b, acc, 0, 0, 0); \
    } } while (0)

__global__ __launch_bounds__(512, 4) void mlm_mfma(
    const float* __restrict__ p_seq, const float* __restrict__ fb,
    const float* __restrict__ ws, float* __restrict__ out) {

    __shared__ __align__(16) char smem[FRAG_BYTES_TOTAL];
    const int tid  = threadIdx.x;
    const int lane = tid & 63;
    const int wv   = tid >> 6;
    const int pair = blockIdx.x * 8 + wv;
    const int lane16 = lane * 16;
    const int row  = lane & 31;            // A-operand row = timestep t
    const int kofs = (lane >> 5) * 4;

    {   // stage both levels' B-fragments into LDS (56 KB, 512 thr x 7 float4)
        const float4* src = reinterpret_cast<const float4*>(
            reinterpret_cast<const char*>(ws) + (size_t)FRAG_OFF * 4);
        float4* dst = reinterpret_cast<float4*>(smem);
#pragma unroll
        for (int it = 0; it < 7; ++it) dst[tid + it * 512] = src[tid + it * 512];
    }

    // ---- A fragments: hi/lo bf16 split of X rows (exact 2-term on x side) ----
    s16x8 Ah[4], Al[4];
    {
        const float* X = p_seq + (size_t)pair * (LL * DD) + row * 64 + kofs;
#pragma unroll
        for (int ks = 0; ks < 4; ++ks) {
            const float4 v0 = *reinterpret_cast<const float4*>(X + ks * 16);
            const float4 v1 = *reinterpret_cast<const float4*>(X + ks * 16 + 8);
            float f[8] = {v0.x, v0.y, v0.z, v0.w, v1.x, v1.y, v1.z, v1.w};
#pragma unroll
            for (int i = 0; i < 8; ++i) {
                unsigned u = __float_as_uint(f[i]);
                float hf = __uint_as_float(u & 0xffff0000u);
                Ah[ks][i] = (short)(u >> 16);
                Al[ks][i] = (short)(__float_as_uint(f[i] - hf) >> 16);
            }
        }
    }
    __syncthreads();

    const int myhalf = lane >> 5;
    // scan over t held in D-tile regs: t = (r&3) + 8*(r>>2) + 4*(lane>>5)
    auto scan_h = [&](const f32x16& aT, const f32x16& bT, const f32x16& xmT) -> float {
        float h = 0.f;
#pragma unroll
        for (int blk = 0; blk < 4; ++blk) {
            const int rb = blk * 4;
            float s0 = 1.f / (1.f + __expf(-aT[rb + 0]));
            float s1 = 1.f / (1.f + __expf(-aT[rb + 1]));
            float s2 = 1.f / (1.f + __expf(-aT[rb + 2]));
            float s3 = 1.f / (1.f + __expf(-aT[rb + 3]));
            float x0 = bT[rb + 0] * xmT[rb + 0];
            float x1 = bT[rb + 1] * xmT[rb + 1];
            float x2 = bT[rb + 2] * xmT[rb + 2];
            float x3 = bT[rb + 3] * xmT[rb + 3];
            // step A: t = 8*blk .. +3 (owner = half0)
            float hh = fmaf(s0, h, x0); hh = fmaf(s1, hh, x1);
            hh = fmaf(s2, hh, x2);      hh = fmaf(s3, hh, x3);
            float ho = __shfl_xor(hh, 32);
            h = (myhalf == 0) ? hh : ho;
            // step B: t = 8*blk+4 .. +7 (owner = half1, same regs)
            hh = fmaf(s0, h, x0); hh = fmaf(s1, hh, x1);
            hh = fmaf(s2, hh, x2); hh = fmaf(s3, hh, x3);
            ho = __shfl_xor(hh, 32);
            h = (myhalf == 1) ? hh : ho;
        }
        return h;
    };

    float yp = 0.f;
    const float c0sum = ws[C0_OFF] + ws[C0_OFF + 1] + fb[0];

#pragma unroll 1
    for (int l = 0; l < 2; ++l) {
        const float* bias = ws + BIAS_OFF + l * 224;
        const int col = lane & 31;

        f32x16 xmT; ACCINIT(xmT, bias[128 + col]);   // nt4: xm replicated columns
        MX1(l, xmT);

        f32x16 tA, tB;
        ACCINIT(tA, bias[0 + col]);   ACCINIT(tB, bias[64 + col]);   // nt0 (a, s0-31), nt2 (b, s0-31)
        MMP(l, 0, 2, tA, tB);
        float h0 = scan_h(tA, tB, xmT);

        ACCINIT(tA, bias[32 + col]);  ACCINIT(tB, bias[96 + col]);   // nt1 (a, s32-63), nt3 (b, s32-63)
        MMP(l, 1, 3, tA, tB);
        float h1 = scan_h(tA, tB, xmT);

        ACCINIT(tA, bias[160 + col]); ACCINIT(tB, bias[192 + col]);  // nt5, nt6: c columns
        MMP(l, 5, 6, tA, tB);

        // epilogue: reg15 in upper half = t=31
        if (lane >= 32) {
            float xml = xmT[15];
            float x0 = tA[15] * h0;                    // c[s=lane-32] * h0[s]
            float x1 = tB[15] * h1;                    // c[s=lane]    * h1[s]
            float g0 = 0.5f * x0 * (1.f + erff(x0 * 0.70710678118654752440f));
            float g1 = 0.5f * x1 * (1.f + erff(x1 * 0.70710678118654752440f));
            float term = g0 * ws[WVEC_OFF + l * 64 + (lane - 32)]
                       + g1 * ws[WVEC_OFF + l * 64 + lane];
            if (lane == 32) term += xml * ws[SIG_OFF + l] + ws[BETA_OFF + l];
            yp += term;
        }
    }

#pragma unroll
    for (int off = 16; off >= 1; off >>= 1) yp += __shfl_xor(yp, off);
    if (lane == 32) out[pair] = yp + c0sum;
}

extern "C" void kernel_launch(void* const* d_in, const int* in_sizes, int n_in,
                              void* d_out, int out_size, void* d_ws, size_t ws_size,
                              hipStream_t stream) {
    const float* p_seq = (const float*)d_in[0];
    const float* lp_W  = (const float*)d_in[1];
    const float* lp_b  = (const float*)d_in[2];
    const float* pW    = (const float*)d_in[3];
    const float* pb    = (const float*)d_in[4];
    const float* oW    = (const float*)d_in[5];
    const float* ob    = (const float*)d_in[6];
    const float* rW    = (const float*)d_in[7];
    const float* rb    = (const float*)d_in[8];
    const float* fW    = (const float*)d_in[9];
    const float* fb    = (const float*)d_in[10];

    float* ws  = (float*)d_ws;
    float* out = (float*)d_out;

    prep1<<<2 * 224 + 2, 64, 0, stream>>>(lp_W, lp_b, pW, pb, oW, ob, rW, rb, fW, ws);
    prep2<<<2 * 28, 64, 0, stream>>>(ws);

    const int pairs = BB * NN;               // 32768, 8 pairs per block
    mlm_mfma<<<pairs / 8, 512, 0, stream>>>(p_seq, fb, ws, out);
}